// Round 3
// baseline (31157.584 us; speedup 1.0000x reference)
//
#include <hip/hip_runtime.h>
#include <hip/hip_cooperative_groups.h>

namespace cg = cooperative_groups;

#define H 1024
#define V 32000
#define STEPS 375
#define NBLK 256
#define NTHR 512
#define WPB 8              // waves per block
#define RPB 125            // lin_W rows per block
#define GRUROWS 4          // GRU output rows per block

// lin_W row partition within a block (all relative to r0 = b*RPB):
#define REGR 7                       // reg rows per wave
#define NREGROWS (REGR * WPB)        // 56 rows in registers
#define NLDSROWS 15                  // resident LDS rows (56..70)
#define STREAM0 (NREGROWS + NLDSROWS)  // 71
#define NSTREAM (RPB - STREAM0)      // 54 streamed rows
#define CHROWS 8
#define NCH 7                        // 6 chunks of 8 + 1 chunk of 6

// dynamic LDS layout (bytes)
#define LDS_RES 0                    // 15 rows * 4096 = 61440
#define LDS_BUF0 61440
#define LDS_BUF1 (61440 + 32768)
#define LDS_TOTAL (61440 + 2 * 32768)  // 126976

__device__ __forceinline__ float dot4(const float4 a, const float4 b) {
    return fmaf(a.x, b.x, fmaf(a.y, b.y, fmaf(a.z, b.z, a.w * b.w)));
}

__device__ __forceinline__ float wave_sum(float v) {
#pragma unroll
    for (int off = 32; off > 0; off >>= 1) v += __shfl_xor(v, off);
    return v;
}

__device__ __forceinline__ float wave_max(float v) {
#pragma unroll
    for (int off = 32; off > 0; off >>= 1) v = fmaxf(v, __shfl_xor(v, off));
    return v;
}

__device__ __forceinline__ int argmax_tok(const float* pm_p, const int* pa_p, int lane) {
    float m = -3.4e38f;
    int a = 0x7fffffff;
#pragma unroll
    for (int k = 0; k < NBLK / 64; ++k) {
        float km = pm_p[k * 64 + lane];
        int ka = pa_p[k * 64 + lane];
        if (km > m || (km == m && ka < a)) { m = km; a = ka; }
    }
#pragma unroll
    for (int off = 32; off > 0; off >>= 1) {
        float om = __shfl_xor(m, off);
        int oa = __shfl_xor(a, off);
        if (om > m || (om == m && oa < a)) { m = om; a = oa; }
    }
    return a;
}

__device__ __forceinline__ float finalize_logZ(const float* pm_p, const float* ps_p, int lane) {
    float mt[4], st[4];
#pragma unroll
    for (int k = 0; k < 4; ++k) {
        mt[k] = pm_p[k * 64 + lane];
        st[k] = ps_p[k * 64 + lane];
    }
    float m = fmaxf(fmaxf(mt[0], mt[1]), fmaxf(mt[2], mt[3]));
    m = wave_max(m);
    float se = st[0] * expf(mt[0] - m) + st[1] * expf(mt[1] - m) +
               st[2] * expf(mt[2] - m) + st[3] * expf(mt[3] - m);
    se = wave_sum(se);
    return m + logf(se);
}

// Stage `nbytes_pw` bytes (this wave's share) of a chunk into LDS via
// global_load_lds (16 B/lane, wave-uniform LDS base + lane*16 scatter).
__device__ __forceinline__ void stage_chunk(const float* gbase, uint8_t* smem,
                                            int bufoff, int nbytes_pw, int w, int lane) {
    for (int j = 0; j * 1024 < nbytes_pw; ++j) {
        const int off = w * nbytes_pw + j * 1024;
        const uint32_t* gp = (const uint32_t*)gbase + (off >> 2) + lane * 4;
        __builtin_amdgcn_global_load_lds(
            (const __attribute__((address_space(1))) uint32_t*)gp,
            (__attribute__((address_space(3))) uint32_t*)(smem + bufoff + off),
            16, 0, 0);
    }
}

__global__ __launch_bounds__(NTHR, 2) void decoder_kernel(
    const float* __restrict__ enc, const float* __restrict__ emb,
    const float* __restrict__ W_ih, const float* __restrict__ W_hh,
    const float* __restrict__ b_ih, const float* __restrict__ b_hh,
    const float* __restrict__ lin_W, const float* __restrict__ lin_b,
    float* __restrict__ out, float* __restrict__ ws) {
    cg::grid_group grid = cg::this_grid();
    extern __shared__ uint8_t smem[];
    const int tid = threadIdx.x;
    const int lane = tid & 63;
    const int wv = tid >> 6;
    const int b = blockIdx.x;
    const int r0 = b * RPB;

    float* h_buf = ws;                   // [2][H]
    float* pm = ws + 2 * H;              // [2][NBLK]
    float* psum = pm + 2 * NBLK;         // [2][NBLK]
    int* parg = (int*)(psum + 2 * NBLK); // [2][NBLK]

    __shared__ float gpA[3][GRUROWS], gpB[3][GRUROWS];
    __shared__ float red_m[WPB], red_s[WPB];
    __shared__ int red_a[WPB];

    // ---------- one-time: weights into registers / resident LDS ----------
    float4 wg[3][4];    // 3 GRU weight rows per wave (48 VGPR)
#pragma unroll
    for (int k = 0; k < 3; ++k) {
        const int q = wv * 3 + k;           // 0..23; q<12 -> W_ih, else W_hh
        const int q12 = q - (q >= 12 ? 12 : 0);
        const int g = q12 >> 2, r = q12 & 3;
        const float* Wb = (q < 12) ? W_ih : W_hh;
        const float4* rp = (const float4*)(Wb + ((size_t)g * H + b * GRUROWS + r) * H);
#pragma unroll
        for (int j = 0; j < 4; ++j) wg[k][j] = rp[lane + 64 * j];
    }
    float4 wlin[REGR][4];  // 7 lin_W rows per wave (112 VGPR)
#pragma unroll
    for (int k = 0; k < REGR; ++k) {
        const float4* rp = (const float4*)(lin_W + (size_t)(r0 + wv * REGR + k) * H);
#pragma unroll
        for (int j = 0; j < 4; ++j) wlin[k][j] = rp[lane + 64 * j];
    }
    {   // resident LDS rows (once)
        float4* sres = (float4*)smem;
        const float4* gsrc = (const float4*)(lin_W + (size_t)(r0 + NREGROWS) * H);
        for (int idx = tid; idx < NLDSROWS * H / 4; idx += NTHR) sres[idx] = gsrc[idx];
    }
    if (b == 0)
        for (int i = tid; i < H; i += NTHR) h_buf[i] = enc[i];
    __syncthreads();
    grid.sync();

    for (int s = 0; s < STEPS; ++s) {
        const int par = s & 1;
        const float* h_cur = h_buf + par * H;
        float* h_next = h_buf + (par ^ 1) * H;

        // ================= phase A: GRU from registers (+ finalize prev) =====
        {
            const float4* vsrc;
            if (wv < 4) {   // W_ih rows: need x = emb[argmax]
                int tok = 0;
                if (s > 0) {
                    const int pp = (s - 1) & 1;
                    tok = argmax_tok(pm + pp * NBLK, parg + pp * NBLK, lane);
                }
                vsrc = (const float4*)(emb + (size_t)tok * H);
            } else {
                vsrc = (const float4*)h_cur;
            }
            float4 vr[4];
#pragma unroll
            for (int j = 0; j < 4; ++j) vr[j] = vsrc[lane + 64 * j];
#pragma unroll
            for (int k = 0; k < 3; ++k) {
                float a = 0.f;
#pragma unroll
                for (int j = 0; j < 4; ++j) a += dot4(wg[k][j], vr[j]);
                a = wave_sum(a);
                if (lane == 0) {
                    const int q = wv * 3 + k;
                    const int q12 = q - (q >= 12 ? 12 : 0);
                    const int g = q12 >> 2, r = q12 & 3;
                    const float bias = (q < 12) ? b_ih[g * H + b * GRUROWS + r]
                                                : b_hh[g * H + b * GRUROWS + r];
                    if (q < 12) gpA[g][r] = a + bias;
                    else gpB[g][r] = a + bias;
                }
            }
            if (wv >= 4 && s > 0) {   // finalize previous step's logp
                const int pp = (s - 1) & 1;
                const float logZ = finalize_logZ(pm + pp * NBLK, psum + pp * NBLK, lane);
                const int t2 = tid - 4 * 64;  // 0..255
                if (t2 < RPB) out[(size_t)(s - 1) * V + r0 + t2] -= logZ;
            }
        }
        __syncthreads();
        if (wv == 0 && lane < GRUROWS) {
            const int r = lane;
            const float rg = 1.f / (1.f + expf(-(gpA[0][r] + gpB[0][r])));
            const float zg = 1.f / (1.f + expf(-(gpA[1][r] + gpB[1][r])));
            const float ng = tanhf(gpA[2][r] + rg * gpB[2][r]);
            const int i = b * GRUROWS + r;
            h_next[i] = (1.f - zg) * ng + zg * h_cur[i];
        }
        grid.sync();

        // ================= phase B: logits =================
        {
            const float4* h4 = (const float4*)h_next;
            float4 hr[4];
#pragma unroll
            for (int j = 0; j < 4; ++j) hr[j] = h4[lane + 64 * j];

            // issue chunk 0 stage early; its flight is covered by reg/LDS rows
            stage_chunk(lin_W + (size_t)(r0 + STREAM0) * H, smem, LDS_BUF0,
                        CHROWS * 512, wv, lane);

            float lg[16];
            float m = -3.4e38f, ssum = 0.f;
            int arg = 0x7fffffff;
            // slots 0..6: register rows (cols r0 + wv*7 + k)
#pragma unroll
            for (int k = 0; k < REGR; ++k) {
                float a = 0.f;
#pragma unroll
                for (int j = 0; j < 4; ++j) a += dot4(wlin[k][j], hr[j]);
                a = wave_sum(a) + lin_b[r0 + wv * REGR + k];
                lg[k] = a;
                const int col = r0 + wv * REGR + k;
                if (a > m) { ssum *= expf(m - a); m = a; arg = col; }
                ssum += expf(a - m);
            }
            // slot 7: LDS-resident row 56+wv ; slot 8: row 64+wv (wv<7)
#pragma unroll
            for (int p = 0; p < 2; ++p) {
                const int lr = p * 8 + wv;          // 0..14
                if (p == 0 || wv < 7) {
                    const float4* rp = (const float4*)(smem + LDS_RES + lr * 4096);
                    float a = 0.f;
#pragma unroll
                    for (int j = 0; j < 4; ++j) a += dot4(rp[lane + 64 * j], hr[j]);
                    const int col = r0 + NREGROWS + lr;
                    a = wave_sum(a) + lin_b[col];
                    lg[7 + p] = a;
                    if (a > m) { ssum *= expf(m - a); m = a; arg = col; }
                    ssum += expf(a - m);
                }
            }
            // streamed chunks, double-buffered global_load_lds pipeline
#pragma unroll
            for (int t = 0; t < NCH; ++t) {
                const int CR = (t < NCH - 1) ? CHROWS : (NSTREAM - (NCH - 1) * CHROWS);
                const int bufoff = (t & 1) ? LDS_BUF1 : LDS_BUF0;
                __syncthreads();   // compiler drains vmcnt -> chunk t landed
                if (t + 1 < NCH) {
                    const int CRn = (t + 1 < NCH - 1) ? CHROWS : (NSTREAM - (NCH - 1) * CHROWS);
                    stage_chunk(lin_W + (size_t)(r0 + STREAM0 + (t + 1) * CHROWS) * H,
                                smem, (t & 1) ? LDS_BUF0 : LDS_BUF1, CRn * 512, wv, lane);
                }
                if (wv < CR) {
                    const float4* rp = (const float4*)(smem + bufoff + wv * 4096);
                    float a = 0.f;
#pragma unroll
                    for (int j = 0; j < 4; ++j) a += dot4(rp[lane + 64 * j], hr[j]);
                    const int col = r0 + STREAM0 + t * CHROWS + wv;
                    a = wave_sum(a) + lin_b[col];
                    lg[9 + t] = a;
                    if (a > m) { ssum *= expf(m - a); m = a; arg = col; }
                    ssum += expf(a - m);
                }
            }
            // store this wave's logits (raw; logZ subtracted next step)
            if (lane == 0) {
                float* orow = out + (size_t)s * V + r0;
#pragma unroll
                for (int k = 0; k < REGR; ++k) orow[wv * REGR + k] = lg[k];
                orow[NREGROWS + wv] = lg[7];
                if (wv < 7) orow[NREGROWS + 8 + wv] = lg[8];
#pragma unroll
                for (int t = 0; t < NCH; ++t) {
                    const int CR = (t < NCH - 1) ? CHROWS : (NSTREAM - (NCH - 1) * CHROWS);
                    if (wv < CR) orow[STREAM0 + t * CHROWS + wv] = lg[9 + t];
                }
            }
            if (lane == 0) { red_m[wv] = m; red_s[wv] = ssum; red_a[wv] = arg; }
            __syncthreads();
            if (tid == 0) {
                float M = -3.4e38f, S = 0.f;
                int A = 0x7fffffff;
#pragma unroll
                for (int w = 0; w < WPB; ++w) {
                    float mw = red_m[w], sw = red_s[w];
                    int aw = red_a[w];
                    if (mw > M || (mw == M && aw < A)) {
                        S = S * expf(M - mw) + sw; M = mw; A = aw;
                    } else {
                        S += sw * expf(mw - M);
                    }
                }
                pm[par * NBLK + b] = M;
                psum[par * NBLK + b] = S;
                parg[par * NBLK + b] = A;
            }
        }
        grid.sync();
    }

    // ---- finalize last step's logp
    {
        const int pp = (STEPS - 1) & 1;
        const float logZ = finalize_logZ(pm + pp * NBLK, psum + pp * NBLK, lane);
        if (tid < RPB) out[(size_t)(STEPS - 1) * V + r0 + tid] -= logZ;
    }
    // ---- final hidden state
    if (b == 0) {
        const float* hf = h_buf + (STEPS & 1) * H;
        for (int i = tid; i < H; i += NTHR) out[(size_t)V * STEPS + i] = hf[i];
    }
}

extern "C" void kernel_launch(void* const* d_in, const int* in_sizes, int n_in,
                              void* d_out, int out_size, void* d_ws, size_t ws_size,
                              hipStream_t stream) {
    const float* enc = (const float*)d_in[0];
    const float* emb = (const float*)d_in[1];
    const float* W_ih = (const float*)d_in[2];
    const float* W_hh = (const float*)d_in[3];
    const float* b_ih = (const float*)d_in[4];
    const float* b_hh = (const float*)d_in[5];
    const float* lin_W = (const float*)d_in[6];
    const float* lin_b = (const float*)d_in[7];
    float* out = (float*)d_out;
    float* ws = (float*)d_ws;

    void* args[] = {&enc, &emb, &W_ih, &W_hh, &b_ih, &b_hh, &lin_W, &lin_b, &out, &ws};
    hipLaunchCooperativeKernel(reinterpret_cast<const void*>(&decoder_kernel),
                               dim3(NBLK), dim3(NTHR), args, LDS_TOTAL, stream);
}

// Round 4
// 29539.084 us; speedup vs baseline: 1.0548x; 1.0548x over previous
//
#include <hip/hip_runtime.h>
#include <hip/hip_cooperative_groups.h>

namespace cg = cooperative_groups;

#define H 1024
#define V 32000
#define STEPS 375
#define NBLK 256
#define NTHR 512
#define WPB 8              // waves per block
#define RPB 125            // lin_W rows per block
#define GRUROWS 4          // GRU output rows per block

// lin_W row partition within a block (relative to r0 = b*RPB):
#define REGR 7                         // reg rows per wave
#define NREGROWS (REGR * WPB)          // 56 rows in registers
#define NLDSROWS 15                    // resident LDS rows
#define STREAM0 (NREGROWS + NLDSROWS)  // 71
#define NSTREAM (RPB - STREAM0)        // 54 streamed rows
#define CHROWS 8
#define NCH 7                          // 6 chunks of 8 + 1 of 6

// dynamic LDS layout (bytes)
#define LDS_RES 0
#define LDS_BUF0 61440
#define LDS_BUF1 (61440 + 32768)
#define LDS_TOTAL (61440 + 2 * 32768)  // 126976

__device__ __forceinline__ float dot4(const float4 a, const float4 b) {
    return fmaf(a.x, b.x, fmaf(a.y, b.y, fmaf(a.z, b.z, a.w * b.w)));
}
__device__ __forceinline__ float dot4c(const float4 w, const float* v) {
    return fmaf(w.x, v[0], fmaf(w.y, v[1], fmaf(w.z, v[2], w.w * v[3])));
}

__device__ __forceinline__ float wave_sum(float v) {
#pragma unroll
    for (int off = 32; off > 0; off >>= 1) v += __shfl_xor(v, off);
    return v;
}
__device__ __forceinline__ float wave_max(float v) {
#pragma unroll
    for (int off = 32; off > 0; off >>= 1) v = fmaxf(v, __shfl_xor(v, off));
    return v;
}

// ---- device-scope (cross-XCD coherent) accessors ----
__device__ __forceinline__ void st_agent_f(float* p, float v) {
    __hip_atomic_store(p, v, __ATOMIC_RELAXED, __HIP_MEMORY_SCOPE_AGENT);
}
__device__ __forceinline__ void st_agent_i(int* p, int v) {
    __hip_atomic_store(p, v, __ATOMIC_RELAXED, __HIP_MEMORY_SCOPE_AGENT);
}
__device__ __forceinline__ float ld_agent_f(const float* p) {
    return __hip_atomic_load(p, __ATOMIC_RELAXED, __HIP_MEMORY_SCOPE_AGENT);
}
__device__ __forceinline__ int ld_agent_i(const int* p) {
    return __hip_atomic_load(p, __ATOMIC_RELAXED, __HIP_MEMORY_SCOPE_AGENT);
}

// Wait until all NBLK epoch flags reach `target`. Vectorized: 4 flags/lane.
__device__ __forceinline__ void wait_flags(const int* flags, int target, int lane) {
    for (;;) {
        int f0 = ld_agent_i(flags + lane);
        int f1 = ld_agent_i(flags + lane + 64);
        int f2 = ld_agent_i(flags + lane + 128);
        int f3 = ld_agent_i(flags + lane + 192);
        int mn = min(min(f0, f1), min(f2, f3));
        if (__all(mn >= target)) break;
        __builtin_amdgcn_s_sleep(1);
    }
    __builtin_amdgcn_fence(__ATOMIC_ACQUIRE, "agent");
}

__device__ __forceinline__ int argmax_tok(const float* pm_p, const int* pa_p, int lane) {
    float m = -3.4e38f;
    int a = 0x7fffffff;
#pragma unroll
    for (int k = 0; k < NBLK / 64; ++k) {
        float km = ld_agent_f(pm_p + k * 64 + lane);
        int ka = ld_agent_i(pa_p + k * 64 + lane);
        if (km > m || (km == m && ka < a)) { m = km; a = ka; }
    }
#pragma unroll
    for (int off = 32; off > 0; off >>= 1) {
        float om = __shfl_xor(m, off);
        int oa = __shfl_xor(a, off);
        if (om > m || (om == m && oa < a)) { m = om; a = oa; }
    }
    return a;
}

__device__ __forceinline__ float finalize_logZ(const float* pm_p, const float* ps_p, int lane) {
    float mt[4], st[4];
#pragma unroll
    for (int k = 0; k < 4; ++k) {
        mt[k] = ld_agent_f(pm_p + k * 64 + lane);
        st[k] = ld_agent_f(ps_p + k * 64 + lane);
    }
    float m = fmaxf(fmaxf(mt[0], mt[1]), fmaxf(mt[2], mt[3]));
    m = wave_max(m);
    float se = st[0] * expf(mt[0] - m) + st[1] * expf(mt[1] - m) +
               st[2] * expf(mt[2] - m) + st[3] * expf(mt[3] - m);
    se = wave_sum(se);
    return m + logf(se);
}

__device__ __forceinline__ void stage_chunk(const float* gbase, uint8_t* smem,
                                            int bufoff, int nbytes_pw, int w, int lane) {
    for (int j = 0; j * 1024 < nbytes_pw; ++j) {
        const int off = w * nbytes_pw + j * 1024;
        const uint32_t* gp = (const uint32_t*)gbase + (off >> 2) + lane * 4;
        __builtin_amdgcn_global_load_lds(
            (const __attribute__((address_space(1))) uint32_t*)gp,
            (__attribute__((address_space(3))) uint32_t*)(smem + bufoff + off),
            16, 0, 0);
    }
}

__global__ __launch_bounds__(NTHR, 2) void decoder_kernel(
    const float* __restrict__ enc, const float* __restrict__ emb,
    const float* __restrict__ W_ih, const float* __restrict__ W_hh,
    const float* __restrict__ b_ih, const float* __restrict__ b_hh,
    const float* __restrict__ lin_W, const float* __restrict__ lin_b,
    float* __restrict__ out, float* __restrict__ ws) {
    cg::grid_group grid = cg::this_grid();
    extern __shared__ uint8_t smem[];
    const int tid = threadIdx.x;
    const int lane = tid & 63;
    const int wv = tid >> 6;
    const int b = blockIdx.x;
    const int r0 = b * RPB;

    // ws layout
    float* h_buf = ws;                     // [2][H]
    float* pm = ws + 2 * H;                // [2][NBLK]
    float* psum = pm + 2 * NBLK;           // [2][NBLK]
    int* parg = (int*)(psum + 2 * NBLK);   // [2][NBLK]
    int* hflag = parg + 2 * NBLK;          // [NBLK] epoch: h[s] published
    int* pflag = hflag + NBLK;             // [NBLK] epoch: partials[s-1] published

    __shared__ float gpA[3][GRUROWS], gpB[3][GRUROWS];
    __shared__ float red_m[WPB], red_s[WPB];
    __shared__ int red_a[WPB];

    // ---------- one-time: weights into registers / resident LDS ----------
    float4 wg[3][4];
#pragma unroll
    for (int k = 0; k < 3; ++k) {
        const int q = wv * 3 + k;
        const int q12 = q - (q >= 12 ? 12 : 0);
        const int g = q12 >> 2, r = q12 & 3;
        const float* Wb = (q < 12) ? W_ih : W_hh;
        const float4* rp = (const float4*)(Wb + ((size_t)g * H + b * GRUROWS + r) * H);
#pragma unroll
        for (int j = 0; j < 4; ++j) wg[k][j] = rp[lane + 64 * j];
    }
    float4 wlin[REGR][4];
#pragma unroll
    for (int k = 0; k < REGR; ++k) {
        const float4* rp = (const float4*)(lin_W + (size_t)(r0 + wv * REGR + k) * H);
#pragma unroll
        for (int j = 0; j < 4; ++j) wlin[k][j] = rp[lane + 64 * j];
    }
    {
        float4* sres = (float4*)smem;
        const float4* gsrc = (const float4*)(lin_W + (size_t)(r0 + NREGROWS) * H);
        for (int idx = tid; idx < NLDSROWS * H / 4; idx += NTHR) sres[idx] = gsrc[idx];
    }
    // flags + h init (deterministic every call), then ONE cooperative sync
    if (tid == 0) { st_agent_i(&hflag[b], 0); st_agent_i(&pflag[b], 0); }
    if (b == 0)
        for (int i = tid; i < H; i += NTHR) st_agent_f(&h_buf[i], enc[i]);
    __syncthreads();
    grid.sync();

    for (int s = 0; s < STEPS; ++s) {
        const int par = s & 1;
        const float* h_cur = h_buf + par * H;
        float* h_next = h_buf + (par ^ 1) * H;

        // ======== phase A: wait partials[s-1]; GRU; finalize prev logp ========
        if (s > 0) wait_flags(pflag, s, lane);

        if (wv < 4) {   // x-side: rows of W_ih against emb[tok]
            int tok = 0;
            if (s > 0) {
                const int pp = (s - 1) & 1;
                tok = argmax_tok(pm + pp * NBLK, parg + pp * NBLK, lane);
            }
            const float4* vsrc = (const float4*)(emb + (size_t)tok * H);
            float4 vr[4];
#pragma unroll
            for (int j = 0; j < 4; ++j) vr[j] = vsrc[lane + 64 * j];
#pragma unroll
            for (int k = 0; k < 3; ++k) {
                float a = 0.f;
#pragma unroll
                for (int j = 0; j < 4; ++j) a += dot4(wg[k][j], vr[j]);
                a = wave_sum(a);
                if (lane == 0) {
                    const int g = (wv * 3 + k) >> 2, r = (wv * 3 + k) & 3;
                    gpA[g][r] = a + b_ih[g * H + b * GRUROWS + r];
                }
            }
        } else {        // h-side: rows of W_hh against h_cur (device-coherent reads)
            float vrs[16];
#pragma unroll
            for (int k = 0; k < 16; ++k)
                vrs[k] = ld_agent_f(h_cur + 256 * (k >> 2) + 4 * lane + (k & 3));
#pragma unroll
            for (int k = 0; k < 3; ++k) {
                float a = 0.f;
#pragma unroll
                for (int j = 0; j < 4; ++j) a += dot4c(wg[k][j], &vrs[4 * j]);
                a = wave_sum(a);
                if (lane == 0) {
                    const int q12 = wv * 3 + k - 12;
                    const int g = q12 >> 2, r = q12 & 3;
                    gpB[g][r] = a + b_hh[g * H + b * GRUROWS + r];
                }
            }
            if (s > 0) {   // finalize previous step's logp (waves 4..7)
                const int pp = (s - 1) & 1;
                const float logZ = finalize_logZ(pm + pp * NBLK, psum + pp * NBLK, lane);
                const int t2 = tid - 4 * 64;
                if (t2 < RPB) out[(size_t)(s - 1) * V + r0 + t2] -= logZ;
            }
        }
        __syncthreads();
        if (wv == 0 && lane < GRUROWS) {
            const int r = lane;
            const int i = b * GRUROWS + r;
            const float rg = 1.f / (1.f + expf(-(gpA[0][r] + gpB[0][r])));
            const float zg = 1.f / (1.f + expf(-(gpA[1][r] + gpB[1][r])));
            const float ng = tanhf(gpA[2][r] + rg * gpB[2][r]);
            st_agent_f(&h_next[i], (1.f - zg) * ng + zg * ld_agent_f(h_cur + i));
            __builtin_amdgcn_fence(__ATOMIC_RELEASE, "agent");
            if (lane == 0) st_agent_i(&hflag[b], s + 1);
        }

        // ======== phase B: logits from h[s+1] ========
        {
            // stage chunk 0 early: overlaps the h rendezvous (BUF0 is safe:
            // pflag poll guaranteed all our waves passed last iter's reads)
            stage_chunk(lin_W + (size_t)(r0 + STREAM0) * H, smem, LDS_BUF0,
                        CHROWS * 512, wv, lane);

            wait_flags(hflag, s + 1, lane);
            float hrs[16];
#pragma unroll
            for (int k = 0; k < 16; ++k)
                hrs[k] = ld_agent_f(h_next + 256 * (k >> 2) + 4 * lane + (k & 3));

            float lg[16];
            float m = -3.4e38f, ssum = 0.f;
            int arg = 0x7fffffff;
#pragma unroll
            for (int k = 0; k < REGR; ++k) {
                float a = 0.f;
#pragma unroll
                for (int j = 0; j < 4; ++j) a += dot4c(wlin[k][j], &hrs[4 * j]);
                a = wave_sum(a) + lin_b[r0 + wv * REGR + k];
                lg[k] = a;
                const int col = r0 + wv * REGR + k;
                if (a > m) { ssum *= expf(m - a); m = a; arg = col; }
                ssum += expf(a - m);
            }
#pragma unroll
            for (int p = 0; p < 2; ++p) {
                const int lr = p * 8 + wv;
                if (p == 0 || wv < 7) {
                    const float4* rp = (const float4*)(smem + LDS_RES + lr * 4096);
                    float a = 0.f;
#pragma unroll
                    for (int j = 0; j < 4; ++j) a += dot4c(rp[lane + 64 * j], &hrs[4 * j]);
                    const int col = r0 + NREGROWS + lr;
                    a = wave_sum(a) + lin_b[col];
                    lg[7 + p] = a;
                    if (a > m) { ssum *= expf(m - a); m = a; arg = col; }
                    ssum += expf(a - m);
                }
            }
#pragma unroll
            for (int t = 0; t < NCH; ++t) {
                const int CR = (t < NCH - 1) ? CHROWS : (NSTREAM - (NCH - 1) * CHROWS);
                const int bufoff = (t & 1) ? LDS_BUF1 : LDS_BUF0;
                __syncthreads();   // own-wave vmcnt drained before barrier -> chunk t landed
                if (t + 1 < NCH) {
                    const int CRn = (t + 1 < NCH - 1) ? CHROWS : (NSTREAM - (NCH - 1) * CHROWS);
                    stage_chunk(lin_W + (size_t)(r0 + STREAM0 + (t + 1) * CHROWS) * H,
                                smem, (t & 1) ? LDS_BUF0 : LDS_BUF1, CRn * 512, wv, lane);
                }
                if (wv < CR) {
                    const float4* rp = (const float4*)(smem + bufoff + wv * 4096);
                    float a = 0.f;
#pragma unroll
                    for (int j = 0; j < 4; ++j) a += dot4c(rp[lane + 64 * j], &hrs[4 * j]);
                    const int col = r0 + STREAM0 + t * CHROWS + wv;
                    a = wave_sum(a) + lin_b[col];
                    lg[9 + t] = a;
                    if (a > m) { ssum *= expf(m - a); m = a; arg = col; }
                    ssum += expf(a - m);
                }
            }
            if (lane == 0) {
                float* orow = out + (size_t)s * V + r0;
#pragma unroll
                for (int k = 0; k < REGR; ++k) orow[wv * REGR + k] = lg[k];
                orow[NREGROWS + wv] = lg[7];
                if (wv < 7) orow[NREGROWS + 8 + wv] = lg[8];
#pragma unroll
                for (int t = 0; t < NCH; ++t) {
                    const int CR = (t < NCH - 1) ? CHROWS : (NSTREAM - (NCH - 1) * CHROWS);
                    if (wv < CR) orow[STREAM0 + t * CHROWS + wv] = lg[9 + t];
                }
                red_m[wv] = m; red_s[wv] = ssum; red_a[wv] = arg;
            }
            __syncthreads();
            if (tid == 0) {
                float M = -3.4e38f, S = 0.f;
                int A = 0x7fffffff;
#pragma unroll
                for (int w = 0; w < WPB; ++w) {
                    float mw = red_m[w], sw = red_s[w];
                    int aw = red_a[w];
                    if (mw > M || (mw == M && aw < A)) {
                        S = S * expf(M - mw) + sw; M = mw; A = aw;
                    } else {
                        S += sw * expf(mw - M);
                    }
                }
                st_agent_f(&pm[par * NBLK + b], M);
                st_agent_f(&psum[par * NBLK + b], S);
                st_agent_i(&parg[par * NBLK + b], A);
                __builtin_amdgcn_fence(__ATOMIC_RELEASE, "agent");
                st_agent_i(&pflag[b], s + 1);
            }
        }
    }

    // ---- finalize last step's logp (needs partials[374] from all blocks)
    wait_flags(pflag, STEPS, lane);
    {
        const int pp = (STEPS - 1) & 1;
        const float logZ = finalize_logZ(pm + pp * NBLK, psum + pp * NBLK, lane);
        if (tid < RPB) out[(size_t)(STEPS - 1) * V + r0 + tid] -= logZ;
    }
    if (b == 0) {
        const float* hf = h_buf + (STEPS & 1) * H;
        for (int i = tid; i < H; i += NTHR)
            out[(size_t)V * STEPS + i] = ld_agent_f(hf + i);
    }
}

extern "C" void kernel_launch(void* const* d_in, const int* in_sizes, int n_in,
                              void* d_out, int out_size, void* d_ws, size_t ws_size,
                              hipStream_t stream) {
    const float* enc = (const float*)d_in[0];
    const float* emb = (const float*)d_in[1];
    const float* W_ih = (const float*)d_in[2];
    const float* W_hh = (const float*)d_in[3];
    const float* b_ih = (const float*)d_in[4];
    const float* b_hh = (const float*)d_in[5];
    const float* lin_W = (const float*)d_in[6];
    const float* lin_b = (const float*)d_in[7];
    float* out = (float*)d_out;
    float* ws = (float*)d_ws;

    void* args[] = {&enc, &emb, &W_ih, &W_hh, &b_ih, &b_hh, &lin_W, &lin_b, &out, &ws};
    hipLaunchCooperativeKernel(reinterpret_cast<const void*>(&decoder_kernel),
                               dim3(NBLK), dim3(NTHR), args, LDS_TOTAL, stream);
}

// Round 5
// 12660.001 us; speedup vs baseline: 2.4611x; 2.3333x over previous
//
#include <hip/hip_runtime.h>

#define H 1024
#define V 32000
#define STEPS 375
#define NB1 256     // gru/tail kernel blocks
#define NB2 512     // logits kernel blocks (2 per CU)
#define RPB1 125    // out cols per gru block (V/NB1)

__device__ __forceinline__ float dot4(const float4 a, const float4 b) {
    return fmaf(a.x, b.x, fmaf(a.y, b.y, fmaf(a.z, b.z, a.w * b.w)));
}

__device__ __forceinline__ float wave_sum(float v) {
#pragma unroll
    for (int off = 32; off > 0; off >>= 1) v += __shfl_xor(v, off);
    return v;
}

// merge (om, os, oa) into running (m, ss, a); max w/ smallest-index tie, scaled sums
__device__ __forceinline__ void sm_merge(float& m, float& ss, int& a,
                                         float om, float os, int oa) {
    if (om > m || (om == m && oa < a)) {
        ss = os + ss * expf(m - om); m = om; a = oa;
    } else {
        ss += os * expf(om - m);
    }
}

// ---------------- init: h0 = enc ----------------
__global__ void init_kernel(const float* __restrict__ enc, float* __restrict__ h0) {
    for (int i = threadIdx.x; i < H; i += 256) h0[i] = enc[i];
}

// ---------------- per-step GRU (+ finalize prev logp) ----------------
__global__ __launch_bounds__(256) void gru_kernel(
    const float* __restrict__ emb, const float* __restrict__ W_ih,
    const float* __restrict__ W_hh, const float* __restrict__ b_ih,
    const float* __restrict__ b_hh, const float* __restrict__ h_cur,
    float* __restrict__ h_next, float* __restrict__ out_prev,
    const float* __restrict__ pm, const float* __restrict__ ps,
    const int* __restrict__ pa, int s) {
    const int tid = threadIdx.x;
    const int lane = tid & 63;
    const int wv = tid >> 6;
    const int b = blockIdx.x;

    int tok = 0;
    if (s > 0) {
        // redundant per-wave reduce of NB2 partials -> (tok, logZ)
        float m = -3.4e38f, ss = 0.f;
        int a = 0x7fffffff;
#pragma unroll
        for (int k = 0; k < NB2 / 64; ++k)
            sm_merge(m, ss, a, pm[k * 64 + lane], ps[k * 64 + lane], pa[k * 64 + lane]);
#pragma unroll
        for (int off = 32; off > 0; off >>= 1) {
            float om = __shfl_xor(m, off), os = __shfl_xor(ss, off);
            int oa = __shfl_xor(a, off);
            sm_merge(m, ss, a, om, os, oa);
        }
        const float logZ = m + logf(ss);
        tok = a;
        if (tid < RPB1) out_prev[b * RPB1 + tid] -= logZ;
    }

    // GRU output row i = b*4 + wv (4 waves, one row each)
    const int i = b * 4 + wv;
    const float4* xp = (const float4*)(emb + (size_t)tok * H);
    const float4* hp = (const float4*)h_cur;
    float4 xv[4], hv[4];
#pragma unroll
    for (int j = 0; j < 4; ++j) {
        xv[j] = xp[lane + 64 * j];
        hv[j] = hp[lane + 64 * j];
    }
    const float4* wx0 = (const float4*)(W_ih + (size_t)i * H);
    const float4* wx1 = (const float4*)(W_ih + ((size_t)i + H) * H);
    const float4* wx2 = (const float4*)(W_ih + ((size_t)i + 2 * H) * H);
    const float4* wh0 = (const float4*)(W_hh + (size_t)i * H);
    const float4* wh1 = (const float4*)(W_hh + ((size_t)i + H) * H);
    const float4* wh2 = (const float4*)(W_hh + ((size_t)i + 2 * H) * H);
    float4 WX0[4], WX1[4], WX2[4], WH0[4], WH1[4], WH2[4];
#pragma unroll
    for (int j = 0; j < 4; ++j) {
        const int idx = lane + 64 * j;
        WX0[j] = wx0[idx]; WX1[j] = wx1[idx]; WX2[j] = wx2[idx];
        WH0[j] = wh0[idx]; WH1[j] = wh1[idx]; WH2[j] = wh2[idx];
    }
    float sx0 = 0, sx1 = 0, sx2 = 0, sh0 = 0, sh1 = 0, sh2 = 0;
#pragma unroll
    for (int j = 0; j < 4; ++j) {
        sx0 += dot4(WX0[j], xv[j]); sx1 += dot4(WX1[j], xv[j]); sx2 += dot4(WX2[j], xv[j]);
        sh0 += dot4(WH0[j], hv[j]); sh1 += dot4(WH1[j], hv[j]); sh2 += dot4(WH2[j], hv[j]);
    }
    sx0 = wave_sum(sx0); sx1 = wave_sum(sx1); sx2 = wave_sum(sx2);
    sh0 = wave_sum(sh0); sh1 = wave_sum(sh1); sh2 = wave_sum(sh2);
    if (lane == 0) {
        const float rg = 1.f / (1.f + expf(-((sx0 + b_ih[i]) + (sh0 + b_hh[i]))));
        const float zg = 1.f / (1.f + expf(-((sx1 + b_ih[i + H]) + (sh1 + b_hh[i + H]))));
        const float ng = tanhf((sx2 + b_ih[i + 2 * H]) + rg * (sh2 + b_hh[i + 2 * H]));
        h_next[i] = (1.f - zg) * ng + zg * h_cur[i];
    }
}

// ---------------- per-step logits GEMV + online-softmax partials ----------------
__global__ __launch_bounds__(512, 4) void logits_kernel(
    const float* __restrict__ lin_W, const float* __restrict__ lin_b,
    const float* __restrict__ h_src, float* __restrict__ orow,
    float* __restrict__ pm, float* __restrict__ ps, int* __restrict__ pa) {
    const int tid = threadIdx.x;
    const int lane = tid & 63;
    const int wv = tid >> 6;
    const int b = blockIdx.x;
    // first 256 blocks: 63 rows, rest: 62 rows (256*63 + 256*62 = 32000)
    const int row0 = (b < 256) ? 63 * b : 16128 + 62 * (b - 256);
    const int nrows = (b < 256) ? 63 : 62;

    __shared__ float red_m[8], red_s[8];
    __shared__ int red_a[8];

    const float4* h4 = (const float4*)h_src;
    float4 hr[4];
#pragma unroll
    for (int j = 0; j < 4; ++j) hr[j] = h4[lane + 64 * j];

    float m = -3.4e38f, ssum = 0.f;
    int arg = 0x7fffffff;
    for (int r = wv; r < nrows; r += 32) {
        const int rB = r + 8, rC = r + 16, rD = r + 24;
        const bool vB = rB < nrows, vC = rC < nrows, vD = rD < nrows;
        const float4* pA = (const float4*)(lin_W + (size_t)(row0 + r) * H);
        const float4* pB = (const float4*)(lin_W + (size_t)(row0 + (vB ? rB : r)) * H);
        const float4* pC = (const float4*)(lin_W + (size_t)(row0 + (vC ? rC : r)) * H);
        const float4* pD = (const float4*)(lin_W + (size_t)(row0 + (vD ? rD : r)) * H);
        float4 wA[4], wB[4], wC[4], wD[4];
#pragma unroll
        for (int j = 0; j < 4; ++j) {
            const int idx = lane + 64 * j;
            wA[j] = pA[idx]; wB[j] = pB[idx]; wC[j] = pC[idx]; wD[j] = pD[idx];
        }
        __builtin_amdgcn_sched_barrier(0);
        float aA = 0, aB = 0, aC = 0, aD = 0;
#pragma unroll
        for (int j = 0; j < 4; ++j) {
            aA += dot4(wA[j], hr[j]); aB += dot4(wB[j], hr[j]);
            aC += dot4(wC[j], hr[j]); aD += dot4(wD[j], hr[j]);
        }
        aA = wave_sum(aA); aB = wave_sum(aB);
        aC = wave_sum(aC); aD = wave_sum(aD);
        aA += lin_b[row0 + r];
        if (lane == 0) __builtin_nontemporal_store(aA, &orow[row0 + r]);
        if (aA > m) { ssum *= expf(m - aA); m = aA; arg = row0 + r; }
        ssum += expf(aA - m);
        if (vB) {
            aB += lin_b[row0 + rB];
            if (lane == 0) __builtin_nontemporal_store(aB, &orow[row0 + rB]);
            if (aB > m) { ssum *= expf(m - aB); m = aB; arg = row0 + rB; }
            ssum += expf(aB - m);
        }
        if (vC) {
            aC += lin_b[row0 + rC];
            if (lane == 0) __builtin_nontemporal_store(aC, &orow[row0 + rC]);
            if (aC > m) { ssum *= expf(m - aC); m = aC; arg = row0 + rC; }
            ssum += expf(aC - m);
        }
        if (vD) {
            aD += lin_b[row0 + rD];
            if (lane == 0) __builtin_nontemporal_store(aD, &orow[row0 + rD]);
            if (aD > m) { ssum *= expf(m - aD); m = aD; arg = row0 + rD; }
            ssum += expf(aD - m);
        }
    }
    if (lane == 0) { red_m[wv] = m; red_s[wv] = ssum; red_a[wv] = arg; }
    __syncthreads();
    if (tid == 0) {
        float M = red_m[0], S = red_s[0];
        int A = red_a[0];
#pragma unroll
        for (int w = 1; w < 8; ++w) sm_merge(M, S, A, red_m[w], red_s[w], red_a[w]);
        pm[b] = M; ps[b] = S; pa[b] = A;
    }
}

// ---------------- tail: finalize out[STEPS-1] + write h_final ----------------
__global__ __launch_bounds__(256) void tail_kernel(
    float* __restrict__ out_last, const float* __restrict__ pm,
    const float* __restrict__ ps, const int* __restrict__ pa,
    const float* __restrict__ h_final, float* __restrict__ out_h) {
    const int tid = threadIdx.x;
    const int lane = tid & 63;
    const int b = blockIdx.x;
    float m = -3.4e38f, ss = 0.f;
    int a = 0x7fffffff;
#pragma unroll
    for (int k = 0; k < NB2 / 64; ++k)
        sm_merge(m, ss, a, pm[k * 64 + lane], ps[k * 64 + lane], pa[k * 64 + lane]);
#pragma unroll
    for (int off = 32; off > 0; off >>= 1) {
        float om = __shfl_xor(m, off), os = __shfl_xor(ss, off);
        int oa = __shfl_xor(a, off);
        sm_merge(m, ss, a, om, os, oa);
    }
    const float logZ = m + logf(ss);
    if (tid < RPB1) out_last[b * RPB1 + tid] -= logZ;
    if (b == 0)
        for (int i = tid; i < H; i += 256) out_h[i] = h_final[i];
}

extern "C" void kernel_launch(void* const* d_in, const int* in_sizes, int n_in,
                              void* d_out, int out_size, void* d_ws, size_t ws_size,
                              hipStream_t stream) {
    const float* enc = (const float*)d_in[0];
    const float* emb = (const float*)d_in[1];
    const float* W_ih = (const float*)d_in[2];
    const float* W_hh = (const float*)d_in[3];
    const float* b_ih = (const float*)d_in[4];
    const float* b_hh = (const float*)d_in[5];
    const float* lin_W = (const float*)d_in[6];
    const float* lin_b = (const float*)d_in[7];
    float* out = (float*)d_out;
    float* ws = (float*)d_ws;

    // ws layout (floats): h_buf[2][H] | pm[NB2] | ps[NB2] | pa[NB2](int)
    float* h_buf = ws;
    float* pm = ws + 2 * H;
    float* ps = pm + NB2;
    int* pa = (int*)(ps + NB2);

    init_kernel<<<1, 256, 0, stream>>>(enc, h_buf);
    for (int s = 0; s < STEPS; ++s) {
        float* h_cur = h_buf + (s & 1) * H;
        float* h_next = h_buf + ((s + 1) & 1) * H;
        float* out_prev = out + (size_t)(s > 0 ? s - 1 : 0) * V;
        gru_kernel<<<NB1, 256, 0, stream>>>(emb, W_ih, W_hh, b_ih, b_hh,
                                            h_cur, h_next, out_prev,
                                            pm, ps, pa, s);
        logits_kernel<<<NB2, 512, 0, stream>>>(lin_W, lin_b, h_next,
                                               out + (size_t)s * V, pm, ps, pa);
    }
    tail_kernel<<<NB1, 256, 0, stream>>>(out + (size_t)(STEPS - 1) * V, pm, ps, pa,
                                         h_buf + (STEPS & 1) * H,
                                         out + (size_t)V * STEPS);
}